// Round 10
// baseline (433.569 us; speedup 1.0000x reference)
//
#include <hip/hip_runtime.h>

typedef unsigned short ushort_t;
typedef __attribute__((ext_vector_type(8))) short short8;
typedef __attribute__((ext_vector_type(4))) float float4v;

#define HW 16384
#define A_BINS 180
#define R_BINS 182
#define AP 188              // A padded by 4 each side
#define CCH 64
#define NB 4
#define NC 256              // NB*CCH, nc-major inner dim of hough buffers
#define MROWS (A_BINS * R_BINS)      // 32760
#define MPROWS (AP * R_BINS)         // 34216

static __device__ __forceinline__ float b2f(ushort_t u) {
    union { unsigned u32; float f; } c; c.u32 = ((unsigned)u) << 16; return c.f;
}
static __device__ __forceinline__ float u2f(unsigned u) {
    union { unsigned u32; float f; } c; c.u32 = u; return c.f;
}
static __device__ __forceinline__ ushort_t f2b(float f) {
    union { float f; unsigned u; } c; c.f = f;
    unsigned r = c.u + 0x7fffu + ((c.u >> 16) & 1u);   // RNE
    return (ushort_t)(r >> 16);
}
static __device__ __forceinline__ float4v cvt4(uint2 u) {
    return (float4v){u2f(u.x << 16), u2f(u.x & 0xffff0000u),
                     u2f(u.y << 16), u2f(u.y & 0xffff0000u)};
}

// ---------------- transpose x [256][16384] f32 -> xT [16384][256] bf16 ----------------
__global__ __launch_bounds__(256) void k_transpose(const float* __restrict__ x,
                                                   ushort_t* __restrict__ xT) {
    __shared__ float tile[64][65];
    int t = threadIdx.x, lane = t & 63, g = t >> 6;
    int pBase = blockIdx.x * 64;     // pixel tile
    int ncBase = blockIdx.y * 64;    // channel tile
#pragma unroll
    for (int i = 0; i < 16; ++i) {
        int ncl = g + i * 4;
        tile[ncl][lane] = x[(size_t)(ncBase + ncl) * HW + pBase + lane];
    }
    __syncthreads();
#pragma unroll
    for (int i = 0; i < 16; ++i) {
        int pl = g + i * 4;
        xT[(size_t)(pBase + pl) * 256 + ncBase + lane] = f2b(tile[lane][pl]);
    }
}

// ---- setup: zero A-pad rows (blocks 0..23) + repack weights (blocks 24..311) ----
__global__ __launch_bounds__(256) void k_setup(ushort_t* __restrict__ ht0,
                                               ushort_t* __restrict__ bufA,
                                               ushort_t* __restrict__ bufB,
                                               const float* __restrict__ w2,
                                               const float* __restrict__ w3,
                                               ushort_t* __restrict__ w2b,
                                               ushort_t* __restrict__ w3b) {
    int blk = blockIdx.x, t = threadIdx.x;
    if (blk < 24) {
        int b = blk >> 3, j = blk & 7;
        int ap = (j < 4) ? j : (184 + (j - 4));
        ushort_t* base = (b == 0 ? ht0 : (b == 1 ? bufA : bufB));
        uint4* p = (uint4*)(base + (size_t)ap * (R_BINS * NC));
        int n16 = R_BINS * NC / 8;
        for (int i = t; i < n16; i += 256) p[i] = (uint4){0, 0, 0, 0};
        return;
    }
    int rep = blk - 24;                  // 0..287
    const float* w = (rep >= 144) ? w3 : w2;
    ushort_t* wb = (rep >= 144) ? w3b : w2b;
    int idx = (rep % 144) * 256 + t;     // 0..36863
    int j = idx & 7;
    int lane = (idx >> 3) & 63;
    int cot = (idx >> 9) & 3;
    int h = (idx >> 11) & 1;
    int k = idx >> 12;
    int co = cot * 16 + (lane & 15);
    int ci = h * 32 + (lane >> 4) * 8 + j;
    wb[idx] = f2b(w[(co * 64 + ci) * 9 + k]);
}

// ---- build per-angle CSR: bin -> pixel list; LDS-staged, coalesced output ----
__global__ __launch_bounds__(256) void k_csr(const int* __restrict__ rho,
                                             int* __restrict__ offs,
                                             ushort_t* __restrict__ plist) {
    __shared__ int hist[4][R_BINS];    // per-wave sub-histograms
    __shared__ int tot[R_BINS];
    __shared__ int offl[R_BINS + 1];
    __shared__ int cur[4][R_BINS];
    __shared__ ushort_t sp[HW];        // 32 KB staging, bin-sorted pixel ids
    int a = blockIdx.x, t = threadIdx.x, lane = t & 63, wv = t >> 6;
    for (int i = t; i < 4 * R_BINS; i += 256) ((int*)hist)[i] = 0;
    __syncthreads();
    const int* rA = rho + (size_t)a * HW;
#pragma unroll 4
    for (int i = 0; i < 64; ++i) {
        int r = rA[t + i * 256];
        atomicAdd(&hist[wv][r], 1);
    }
    __syncthreads();
    if (t < R_BINS) tot[t] = hist[0][t] + hist[1][t] + hist[2][t] + hist[3][t];
    __syncthreads();
    if (wv == 0) {                       // wave-parallel exclusive scan, 3 bins/lane
        int b0 = lane * 3;
        int c0 = (b0     < R_BINS) ? tot[b0]     : 0;
        int c1 = (b0 + 1 < R_BINS) ? tot[b0 + 1] : 0;
        int c2 = (b0 + 2 < R_BINS) ? tot[b0 + 2] : 0;
        int sum = c0 + c1 + c2, inc = sum;
#pragma unroll
        for (int d = 1; d < 64; d <<= 1) {
            int vv = __shfl_up(inc, d);
            if (lane >= d) inc += vv;
        }
        int excl = inc - sum;
        if (b0     < R_BINS) offl[b0]     = excl;
        if (b0 + 1 < R_BINS) offl[b0 + 1] = excl + c0;
        if (b0 + 2 < R_BINS) offl[b0 + 2] = excl + c0 + c1;
        if (lane == 63) offl[R_BINS] = inc;
    }
    __syncthreads();
    if (t < R_BINS) {
        int b = offl[t];
        cur[0][t] = b; b += hist[0][t];
        cur[1][t] = b; b += hist[1][t];
        cur[2][t] = b; b += hist[2][t];
        cur[3][t] = b;
    }
    if (t <= R_BINS) offs[a * (R_BINS + 1) + t] = offl[t];
    __syncthreads();
#pragma unroll 4
    for (int i = 0; i < 64; ++i) {
        int p = t + i * 256;
        int r = rA[p];
        int pos = atomicAdd(&cur[wv][r], 1);
        sp[pos] = (ushort_t)p;
    }
    __syncthreads();
    const uint4* spv = (const uint4*)sp;
    uint4* plv = (uint4*)(plist + (size_t)a * HW);
    for (int i = t; i < HW / 8; i += 256) plv[i] = spv[i];
}

// ---- DHT gather v4: scalarized + index-prefetch pipeline, 128-VGPR budget ----
__global__ __launch_bounds__(256, 4) void k_dht_g4(const ushort_t* __restrict__ xT,
                                                   const int* __restrict__ offs,
                                                   const ushort_t* __restrict__ plist,
                                                   ushort_t* __restrict__ ht0) {
    int a = blockIdx.x, part = blockIdx.y;     // grid (180, 16)
    int t = threadIdx.x, lane = t & 63, wv = t >> 6;
    int wslot = part * 4 + wv;                 // 0..63
    int lo4 = lane << 2;                       // element offset within pixel row
    const uint*  plw = (const uint*)(plist + (size_t)a * HW);   // pixel pairs
    const uint4* plq = (const uint4*)plw;                       // 8 pixels
    const int* offA = offs + a * (R_BINS + 1);
    size_t obase = (size_t)(a + 4) * (R_BINS * NC);
    for (int r = wslot; r < R_BINS; r += 64) {
        int off = __builtin_amdgcn_readfirstlane(offA[r]);
        int end = __builtin_amdgcn_readfirstlane(offA[r + 1]);
        float4v acc = (float4v){0.f, 0.f, 0.f, 0.f};
        int j = off;
        // align j to 8-pixel boundary with scalar singles
        while (j < end && (j & 7)) {
            unsigned up = __builtin_amdgcn_readfirstlane(plw[j >> 1]);
            unsigned p = (j & 1) ? (up >> 16) : (up & 0xffffu);
            acc += cvt4(*(const uint2*)(xT + ((size_t)p << 8) + lo4));
            ++j;
        }
        if (j + 16 <= end) {
            uint4 q0 = plq[j >> 3];
            uint4 q1 = plq[(j >> 3) + 1];
            for (; j + 16 <= end; ) {
                int jn = j + 16;
                uint4 n0, n1;
                bool more = (jn + 16 <= end);
                if (more) {                        // prefetch next group's indices
                    n0 = plq[jn >> 3];
                    n1 = plq[(jn >> 3) + 1];
                }
                unsigned w0 = __builtin_amdgcn_readfirstlane(q0.x);
                unsigned w1 = __builtin_amdgcn_readfirstlane(q0.y);
                unsigned w2 = __builtin_amdgcn_readfirstlane(q0.z);
                unsigned w3 = __builtin_amdgcn_readfirstlane(q0.w);
                unsigned w4 = __builtin_amdgcn_readfirstlane(q1.x);
                unsigned w5 = __builtin_amdgcn_readfirstlane(q1.y);
                unsigned w6 = __builtin_amdgcn_readfirstlane(q1.z);
                unsigned w7 = __builtin_amdgcn_readfirstlane(q1.w);
                uint2 u0 = *(const uint2*)(xT + ((size_t)(w0 & 0xffffu) << 8) + lo4);
                uint2 u1 = *(const uint2*)(xT + ((size_t)(w0 >> 16)     << 8) + lo4);
                uint2 u2 = *(const uint2*)(xT + ((size_t)(w1 & 0xffffu) << 8) + lo4);
                uint2 u3 = *(const uint2*)(xT + ((size_t)(w1 >> 16)     << 8) + lo4);
                uint2 u4 = *(const uint2*)(xT + ((size_t)(w2 & 0xffffu) << 8) + lo4);
                uint2 u5 = *(const uint2*)(xT + ((size_t)(w2 >> 16)     << 8) + lo4);
                uint2 u6 = *(const uint2*)(xT + ((size_t)(w3 & 0xffffu) << 8) + lo4);
                uint2 u7 = *(const uint2*)(xT + ((size_t)(w3 >> 16)     << 8) + lo4);
                uint2 u8 = *(const uint2*)(xT + ((size_t)(w4 & 0xffffu) << 8) + lo4);
                uint2 u9 = *(const uint2*)(xT + ((size_t)(w4 >> 16)     << 8) + lo4);
                uint2 ua = *(const uint2*)(xT + ((size_t)(w5 & 0xffffu) << 8) + lo4);
                uint2 ub = *(const uint2*)(xT + ((size_t)(w5 >> 16)     << 8) + lo4);
                uint2 uc = *(const uint2*)(xT + ((size_t)(w6 & 0xffffu) << 8) + lo4);
                uint2 ud = *(const uint2*)(xT + ((size_t)(w6 >> 16)     << 8) + lo4);
                uint2 ue = *(const uint2*)(xT + ((size_t)(w7 & 0xffffu) << 8) + lo4);
                uint2 uf = *(const uint2*)(xT + ((size_t)(w7 >> 16)     << 8) + lo4);
                acc += cvt4(u0); acc += cvt4(u1); acc += cvt4(u2); acc += cvt4(u3);
                acc += cvt4(u4); acc += cvt4(u5); acc += cvt4(u6); acc += cvt4(u7);
                acc += cvt4(u8); acc += cvt4(u9); acc += cvt4(ua); acc += cvt4(ub);
                acc += cvt4(uc); acc += cvt4(ud); acc += cvt4(ue); acc += cvt4(uf);
                q0 = n0; q1 = n1; j = jn;
            }
        }
        for (; j + 8 <= end; j += 8) {
            uint4 q0 = plq[j >> 3];
            unsigned w0 = __builtin_amdgcn_readfirstlane(q0.x);
            unsigned w1 = __builtin_amdgcn_readfirstlane(q0.y);
            unsigned w2 = __builtin_amdgcn_readfirstlane(q0.z);
            unsigned w3 = __builtin_amdgcn_readfirstlane(q0.w);
            uint2 u0 = *(const uint2*)(xT + ((size_t)(w0 & 0xffffu) << 8) + lo4);
            uint2 u1 = *(const uint2*)(xT + ((size_t)(w0 >> 16)     << 8) + lo4);
            uint2 u2 = *(const uint2*)(xT + ((size_t)(w1 & 0xffffu) << 8) + lo4);
            uint2 u3 = *(const uint2*)(xT + ((size_t)(w1 >> 16)     << 8) + lo4);
            uint2 u4 = *(const uint2*)(xT + ((size_t)(w2 & 0xffffu) << 8) + lo4);
            uint2 u5 = *(const uint2*)(xT + ((size_t)(w2 >> 16)     << 8) + lo4);
            uint2 u6 = *(const uint2*)(xT + ((size_t)(w3 & 0xffffu) << 8) + lo4);
            uint2 u7 = *(const uint2*)(xT + ((size_t)(w3 >> 16)     << 8) + lo4);
            acc += cvt4(u0); acc += cvt4(u1); acc += cvt4(u2); acc += cvt4(u3);
            acc += cvt4(u4); acc += cvt4(u5); acc += cvt4(u6); acc += cvt4(u7);
        }
        while (j < end) {
            unsigned up = __builtin_amdgcn_readfirstlane(plw[j >> 1]);
            unsigned p = (j & 1) ? (up >> 16) : (up & 0xffffu);
            acc += cvt4(*(const uint2*)(xT + ((size_t)p << 8) + lo4));
            ++j;
        }
        unsigned lo = (unsigned)f2b(acc.x) | ((unsigned)f2b(acc.y) << 16);
        unsigned hi = (unsigned)f2b(acc.z) | ((unsigned)f2b(acc.w) << 16);
        *(uint2*)(ht0 + obase + (size_t)r * NC + lo4) = (uint2){lo, hi};
    }
}

// ---- depthwise (9,1) conv + bias + relu: register sliding window along a ----
__global__ __launch_bounds__(256) void k_conv1(const ushort_t* __restrict__ ht0,
                                               const float* __restrict__ w1,
                                               const float* __restrict__ b1,
                                               ushort_t* __restrict__ bufA) {
    int t = threadIdx.x, c = t & 63;
    int r = blockIdx.x;              // 0..181
    int a0 = blockIdx.y * 30;        // output angle base (real coords)
    float wr[9];
#pragma unroll
    for (int k = 0; k < 9; ++k) wr[k] = w1[c * 9 + k];
    float bb = b1[c];
    const ushort_t* ip = ht0 + ((size_t)a0 * R_BINS + r) * NC + t;
    float v[38];
#pragma unroll
    for (int j = 0; j < 38; ++j) v[j] = b2f(ip[(size_t)j * (R_BINS * NC)]);
    ushort_t* op = bufA + ((size_t)(a0 + 4) * R_BINS + r) * NC + t;
#pragma unroll
    for (int i = 0; i < 30; ++i) {
        float s = bb;
#pragma unroll
        for (int k = 0; k < 9; ++k) s = fmaf(v[i + k], wr[k], s);
        op[(size_t)i * (R_BINS * NC)] = f2b(fmaxf(s, 0.f));
    }
}

// ---- dense (9,1) conv as MFMA GEMM: B staged in LDS, 64 rows/wave ----
__global__ __launch_bounds__(256) void k_gemm(const ushort_t* __restrict__ in,
                                              const ushort_t* __restrict__ wb,
                                              const float* __restrict__ bias,
                                              ushort_t* __restrict__ out,
                                              int outRowOff) {
    __shared__ ushort_t Bs[36864];   // 73.7 KB -> 2 blocks/CU
    int t = threadIdx.x, lane = t & 63, wv = t >> 6;
    {
        const uint4* src = (const uint4*)wb;
        uint4* dst = (uint4*)Bs;
        for (int i = t; i < 36864 / 8; i += 256) dst[i] = src[i];
    }
    __syncthreads();
    int m = lane & 15, q = lane >> 4;
    int n = blockIdx.y;
    int rowBase = blockIdx.x * 256 + wv * 64;
    const ushort_t* inN = in + n * 64;
    size_t rof[4];
#pragma unroll
    for (int tl = 0; tl < 4; ++tl) {
        int row = rowBase + tl * 16 + m;
        int rowc = row < MROWS ? row : (MROWS - 1);
        rof[tl] = (size_t)rowc * NC;
    }
    float4v acc[4][4];
#pragma unroll
    for (int tl = 0; tl < 4; ++tl)
#pragma unroll
        for (int i = 0; i < 4; ++i) acc[tl][i] = (float4v){0.f, 0.f, 0.f, 0.f};

#pragma unroll
    for (int k = 0; k < 9; ++k) {
#pragma unroll
        for (int h = 0; h < 2; ++h) {
            const ushort_t* base = inN + (size_t)k * (R_BINS * NC) + h * 32 + q * 8;
            short8 af0 = *(const short8*)(base + rof[0]);
            short8 af1 = *(const short8*)(base + rof[1]);
            short8 af2 = *(const short8*)(base + rof[2]);
            short8 af3 = *(const short8*)(base + rof[3]);
            const ushort_t* bl = Bs + (size_t)((k * 2 + h) * 4) * 512 + lane * 8;
            short8 b0 = *(const short8*)(bl);
            short8 b1v = *(const short8*)(bl + 512);
            short8 b2v = *(const short8*)(bl + 1024);
            short8 b3v = *(const short8*)(bl + 1536);
            acc[0][0] = __builtin_amdgcn_mfma_f32_16x16x32_bf16(af0, b0, acc[0][0], 0, 0, 0);
            acc[0][1] = __builtin_amdgcn_mfma_f32_16x16x32_bf16(af0, b1v, acc[0][1], 0, 0, 0);
            acc[0][2] = __builtin_amdgcn_mfma_f32_16x16x32_bf16(af0, b2v, acc[0][2], 0, 0, 0);
            acc[0][3] = __builtin_amdgcn_mfma_f32_16x16x32_bf16(af0, b3v, acc[0][3], 0, 0, 0);
            acc[1][0] = __builtin_amdgcn_mfma_f32_16x16x32_bf16(af1, b0, acc[1][0], 0, 0, 0);
            acc[1][1] = __builtin_amdgcn_mfma_f32_16x16x32_bf16(af1, b1v, acc[1][1], 0, 0, 0);
            acc[1][2] = __builtin_amdgcn_mfma_f32_16x16x32_bf16(af1, b2v, acc[1][2], 0, 0, 0);
            acc[1][3] = __builtin_amdgcn_mfma_f32_16x16x32_bf16(af1, b3v, acc[1][3], 0, 0, 0);
            acc[2][0] = __builtin_amdgcn_mfma_f32_16x16x32_bf16(af2, b0, acc[2][0], 0, 0, 0);
            acc[2][1] = __builtin_amdgcn_mfma_f32_16x16x32_bf16(af2, b1v, acc[2][1], 0, 0, 0);
            acc[2][2] = __builtin_amdgcn_mfma_f32_16x16x32_bf16(af2, b2v, acc[2][2], 0, 0, 0);
            acc[2][3] = __builtin_amdgcn_mfma_f32_16x16x32_bf16(af2, b3v, acc[2][3], 0, 0, 0);
            acc[3][0] = __builtin_amdgcn_mfma_f32_16x16x32_bf16(af3, b0, acc[3][0], 0, 0, 0);
            acc[3][1] = __builtin_amdgcn_mfma_f32_16x16x32_bf16(af3, b1v, acc[3][1], 0, 0, 0);
            acc[3][2] = __builtin_amdgcn_mfma_f32_16x16x32_bf16(af3, b2v, acc[3][2], 0, 0, 0);
            acc[3][3] = __builtin_amdgcn_mfma_f32_16x16x32_bf16(af3, b3v, acc[3][3], 0, 0, 0);
        }
    }

    ushort_t* outN = out + n * 64;
#pragma unroll
    for (int tl = 0; tl < 4; ++tl) {
#pragma unroll
        for (int cot = 0; cot < 4; ++cot) {
            int co = cot * 16 + m;
            float bv = bias[co];
#pragma unroll
            for (int i = 0; i < 4; ++i) {
                int rowD = rowBase + tl * 16 + q * 4 + i;
                float v = fmaxf(acc[tl][cot][i] + bv, 0.f);
                if (rowD < MROWS) outN[(size_t)(rowD + outRowOff) * NC + co] = f2b(v);
            }
        }
    }
}

// ---- inverse DHT v3: contiguous-window staging (rho monotone in w within a block)
// Block owns 32 consecutive-w pixels; per angle their bins span <=33 contiguous rows.
// Ping-pong LDS windows loaded coalesced one angle ahead; accumulate = broadcast
// ds_read_b64, no gathers, no readfirstlane chains. One barrier per angle.
union SharedIdht {
    struct {
        int rhoL[A_BINS][32];        // 23040 B
        int rsL[A_BINS];             // window start
        int rkL[A_BINS];             // window length in uint4 units (rows*32)
        ushort_t win[2][34 * 256];   // 34816 B ping-pong windows
    } s;
    float tile[256 * 33];            // 33792 B (aliases; used after the loop)
};
__global__ __launch_bounds__(512, 4) void k_idht(const ushort_t* __restrict__ buf3,
                                                 const int* __restrict__ rho,
                                                 float* __restrict__ outp) {
    __shared__ SharedIdht u;
    int t = threadIdx.x, lane = t & 63, wv = t >> 6;   // wv 0..7
    int P0 = blockIdx.x * 32;
    // stage this block's rho columns: [180][32]
    for (int i = t; i < A_BINS * 32; i += 512) {
        int a = i >> 5, px = i & 31;
        u.s.rhoL[a][px] = rho[(size_t)a * HW + P0 + px];
    }
    __syncthreads();
    if (t < A_BINS) {   // window bounds from endpoints (rho monotone in w)
        int e0 = u.s.rhoL[t][0], e1 = u.s.rhoL[t][31];
        int rmin = min(e0, e1), rmax = max(e0, e1);
        u.s.rsL[t] = rmin;
        u.s.rkL[t] = (rmax - rmin + 1) * 32;   // uint4 count (row = 32 uint4)
    }
    __syncthreads();
    {   // prologue: window for a=0
        int rs = u.s.rsL[0], k32 = u.s.rkL[0];
        const uint4* src = (const uint4*)(buf3 + (size_t)rs * NC);
        uint4* dst = (uint4*)u.s.win[0];
        for (int i = t; i < k32; i += 512) dst[i] = src[i];
    }
    __syncthreads();
    float4v acc[4];
#pragma unroll
    for (int i = 0; i < 4; ++i) acc[i] = (float4v){0.f, 0.f, 0.f, 0.f};
    for (int a = 0; a < A_BINS; ++a) {
        if (a + 1 < A_BINS) {   // load next window while accumulating current
            int rs = u.s.rsL[a + 1], k32 = u.s.rkL[a + 1];
            const uint4* src = (const uint4*)(buf3 + ((size_t)(a + 1) * R_BINS + rs) * NC);
            uint4* dst = (uint4*)u.s.win[(a + 1) & 1];
            for (int i = t; i < k32; i += 512) dst[i] = src[i];
        }
        int rs = u.s.rsL[a];
        const ushort_t* wb = u.s.win[a & 1];
        int4 rv = *(const int4*)&u.s.rhoL[a][wv * 4];   // my wave's 4 pixels
        int rr[4] = {rv.x, rv.y, rv.z, rv.w};
#pragma unroll
        for (int i = 0; i < 4; ++i) {
            uint2 g = *(const uint2*)(wb + (size_t)(rr[i] - rs) * NC + lane * 4);
            acc[i] += cvt4(g);
        }
        __syncthreads();
    }
    // transpose via tile (aliases windows -- safe after final barrier)
#pragma unroll
    for (int i = 0; i < 4; ++i) {
        int px = wv * 4 + i;
#pragma unroll
        for (int c = 0; c < 4; ++c)
            u.tile[(lane * 4 + c) * 33 + px] = acc[i][c];
    }
    __syncthreads();
    int px = t & 31, nc0 = t >> 5;    // nc0 0..15
    float* on = outp + P0 + px;
#pragma unroll
    for (int k = 0; k < 16; ++k) {
        int nc = nc0 + k * 16;
        on[(size_t)nc * HW] = u.tile[nc * 33 + px];
    }
}

extern "C" void kernel_launch(void* const* d_in, const int* in_sizes, int n_in,
                              void* d_out, int out_size, void* d_ws, size_t ws_size,
                              hipStream_t stream) {
    const float* x   = (const float*)d_in[0];
    const int*   rho = (const int*)d_in[1];
    const float* w1  = (const float*)d_in[2];
    const float* b1  = (const float*)d_in[3];
    const float* w2  = (const float*)d_in[4];
    const float* b2  = (const float*)d_in[5];
    const float* w3  = (const float*)d_in[6];
    const float* b3  = (const float*)d_in[7];
    float* outp = (float*)d_out;

    char* ws = (char*)d_ws;
    size_t off = 0;
    auto alloc = [&](size_t bytes) -> void* {
        void* p = ws + off;
        off = (off + bytes + 255) & ~(size_t)255;
        return p;
    };
    ushort_t* xT    = (ushort_t*)alloc((size_t)HW * NC * 2);             // 8 MB
    ushort_t* ht0   = (ushort_t*)alloc((size_t)AP * R_BINS * NC * 2);    // 17.5 MB
    ushort_t* bufA  = (ushort_t*)alloc((size_t)AP * R_BINS * NC * 2);    // 17.5 MB
    ushort_t* bufB  = (ushort_t*)alloc((size_t)AP * R_BINS * NC * 2);    // 17.5 MB
    ushort_t* buf3  = (ushort_t*)alloc((size_t)A_BINS * R_BINS * NC * 2);// 16.8 MB
    ushort_t* w2b   = (ushort_t*)alloc(36864 * 2);
    ushort_t* w3b   = (ushort_t*)alloc(36864 * 2);
    int*      offs  = (int*)alloc((size_t)A_BINS * (R_BINS + 1) * 4);    // 132 KB
    ushort_t* plist = (ushort_t*)alloc((size_t)A_BINS * HW * 2);         // 5.9 MB

    k_transpose<<<dim3(256, 4), 256, 0, stream>>>(x, xT);
    k_setup<<<312, 256, 0, stream>>>(ht0, bufA, bufB, w2, w3, w2b, w3b);
    k_csr<<<A_BINS, 256, 0, stream>>>(rho, offs, plist);
    k_dht_g4<<<dim3(A_BINS, 16), 256, 0, stream>>>(xT, offs, plist, ht0);
    k_conv1<<<dim3(R_BINS, 6), 256, 0, stream>>>(ht0, w1, b1, bufA);
    k_gemm<<<dim3(128, NB), 256, 0, stream>>>(bufA, w2b, b2, bufB, 728);
    k_gemm<<<dim3(128, NB), 256, 0, stream>>>(bufB, w3b, b3, buf3, 0);
    k_idht<<<dim3(512), 512, 0, stream>>>(buf3, rho, outp);
}

// Round 11
// 384.993 us; speedup vs baseline: 1.1262x; 1.1262x over previous
//
#include <hip/hip_runtime.h>

typedef unsigned short ushort_t;
typedef __attribute__((ext_vector_type(8))) short short8;
typedef __attribute__((ext_vector_type(4))) float float4v;

#define HW 16384
#define A_BINS 180
#define R_BINS 182
#define AP 188              // A padded by 4 each side
#define CCH 64
#define NB 4
#define NC 256              // NB*CCH, nc-major inner dim of hough buffers
#define MROWS (A_BINS * R_BINS)      // 32760
#define MPROWS (AP * R_BINS)         // 34216

static __device__ __forceinline__ float b2f(ushort_t u) {
    union { unsigned u32; float f; } c; c.u32 = ((unsigned)u) << 16; return c.f;
}
static __device__ __forceinline__ float u2f(unsigned u) {
    union { unsigned u32; float f; } c; c.u32 = u; return c.f;
}
static __device__ __forceinline__ ushort_t f2b(float f) {
    union { float f; unsigned u; } c; c.f = f;
    unsigned r = c.u + 0x7fffu + ((c.u >> 16) & 1u);   // RNE
    return (ushort_t)(r >> 16);
}
static __device__ __forceinline__ float4v cvt4(uint2 u) {
    return (float4v){u2f(u.x << 16), u2f(u.x & 0xffff0000u),
                     u2f(u.y << 16), u2f(u.y & 0xffff0000u)};
}

// ---------------- transpose x [256][16384] f32 -> xT [16384][256] bf16 ----------------
__global__ __launch_bounds__(256) void k_transpose(const float* __restrict__ x,
                                                   ushort_t* __restrict__ xT) {
    __shared__ float tile[64][65];
    int t = threadIdx.x, lane = t & 63, g = t >> 6;
    int pBase = blockIdx.x * 64;     // pixel tile
    int ncBase = blockIdx.y * 64;    // channel tile
#pragma unroll
    for (int i = 0; i < 16; ++i) {
        int ncl = g + i * 4;
        tile[ncl][lane] = x[(size_t)(ncBase + ncl) * HW + pBase + lane];
    }
    __syncthreads();
#pragma unroll
    for (int i = 0; i < 16; ++i) {
        int pl = g + i * 4;
        xT[(size_t)(pBase + pl) * 256 + ncBase + lane] = f2b(tile[lane][pl]);
    }
}

// ---- setup: zero A-pad rows (blocks 0..23) + repack weights (blocks 24..311) ----
__global__ __launch_bounds__(256) void k_setup(ushort_t* __restrict__ ht0,
                                               ushort_t* __restrict__ bufA,
                                               ushort_t* __restrict__ bufB,
                                               const float* __restrict__ w2,
                                               const float* __restrict__ w3,
                                               ushort_t* __restrict__ w2b,
                                               ushort_t* __restrict__ w3b) {
    int blk = blockIdx.x, t = threadIdx.x;
    if (blk < 24) {
        int b = blk >> 3, j = blk & 7;
        int ap = (j < 4) ? j : (184 + (j - 4));
        ushort_t* base = (b == 0 ? ht0 : (b == 1 ? bufA : bufB));
        uint4* p = (uint4*)(base + (size_t)ap * (R_BINS * NC));
        int n16 = R_BINS * NC / 8;
        for (int i = t; i < n16; i += 256) p[i] = (uint4){0, 0, 0, 0};
        return;
    }
    int rep = blk - 24;                  // 0..287
    const float* w = (rep >= 144) ? w3 : w2;
    ushort_t* wb = (rep >= 144) ? w3b : w2b;
    int idx = (rep % 144) * 256 + t;     // 0..36863
    int j = idx & 7;
    int lane = (idx >> 3) & 63;
    int cot = (idx >> 9) & 3;
    int h = (idx >> 11) & 1;
    int k = idx >> 12;
    int co = cot * 16 + (lane & 15);
    int ci = h * 32 + (lane >> 4) * 8 + j;
    wb[idx] = f2b(w[(co * 64 + ci) * 9 + k]);
}

// ---- build per-angle CSR: bin -> pixel list; LDS-staged, coalesced output ----
__global__ __launch_bounds__(256) void k_csr(const int* __restrict__ rho,
                                             int* __restrict__ offs,
                                             ushort_t* __restrict__ plist) {
    __shared__ int hist[4][R_BINS];    // per-wave sub-histograms
    __shared__ int tot[R_BINS];
    __shared__ int offl[R_BINS + 1];
    __shared__ int cur[4][R_BINS];
    __shared__ ushort_t sp[HW];        // 32 KB staging, bin-sorted pixel ids
    int a = blockIdx.x, t = threadIdx.x, lane = t & 63, wv = t >> 6;
    for (int i = t; i < 4 * R_BINS; i += 256) ((int*)hist)[i] = 0;
    __syncthreads();
    const int* rA = rho + (size_t)a * HW;
#pragma unroll 4
    for (int i = 0; i < 64; ++i) {
        int r = rA[t + i * 256];
        atomicAdd(&hist[wv][r], 1);
    }
    __syncthreads();
    if (t < R_BINS) tot[t] = hist[0][t] + hist[1][t] + hist[2][t] + hist[3][t];
    __syncthreads();
    if (wv == 0) {                       // wave-parallel exclusive scan, 3 bins/lane
        int b0 = lane * 3;
        int c0 = (b0     < R_BINS) ? tot[b0]     : 0;
        int c1 = (b0 + 1 < R_BINS) ? tot[b0 + 1] : 0;
        int c2 = (b0 + 2 < R_BINS) ? tot[b0 + 2] : 0;
        int sum = c0 + c1 + c2, inc = sum;
#pragma unroll
        for (int d = 1; d < 64; d <<= 1) {
            int vv = __shfl_up(inc, d);
            if (lane >= d) inc += vv;
        }
        int excl = inc - sum;
        if (b0     < R_BINS) offl[b0]     = excl;
        if (b0 + 1 < R_BINS) offl[b0 + 1] = excl + c0;
        if (b0 + 2 < R_BINS) offl[b0 + 2] = excl + c0 + c1;
        if (lane == 63) offl[R_BINS] = inc;
    }
    __syncthreads();
    if (t < R_BINS) {
        int b = offl[t];
        cur[0][t] = b; b += hist[0][t];
        cur[1][t] = b; b += hist[1][t];
        cur[2][t] = b; b += hist[2][t];
        cur[3][t] = b;
    }
    if (t <= R_BINS) offs[a * (R_BINS + 1) + t] = offl[t];
    __syncthreads();
#pragma unroll 4
    for (int i = 0; i < 64; ++i) {
        int p = t + i * 256;
        int r = rA[p];
        int pos = atomicAdd(&cur[wv][r], 1);
        sp[pos] = (ushort_t)p;
    }
    __syncthreads();
    const uint4* spv = (const uint4*)sp;
    uint4* plv = (uint4*)(plist + (size_t)a * HW);
    for (int i = t; i < HW / 8; i += 256) plv[i] = spv[i];
}

// ---- DHT gather v4: scalarized + index-prefetch pipeline, 128-VGPR budget ----
__global__ __launch_bounds__(256, 4) void k_dht_g4(const ushort_t* __restrict__ xT,
                                                   const int* __restrict__ offs,
                                                   const ushort_t* __restrict__ plist,
                                                   ushort_t* __restrict__ ht0) {
    int a = blockIdx.x, part = blockIdx.y;     // grid (180, 16)
    int t = threadIdx.x, lane = t & 63, wv = t >> 6;
    int wslot = part * 4 + wv;                 // 0..63
    int lo4 = lane << 2;                       // element offset within pixel row
    const uint*  plw = (const uint*)(plist + (size_t)a * HW);   // pixel pairs
    const uint4* plq = (const uint4*)plw;                       // 8 pixels
    const int* offA = offs + a * (R_BINS + 1);
    size_t obase = (size_t)(a + 4) * (R_BINS * NC);
    for (int r = wslot; r < R_BINS; r += 64) {
        int off = __builtin_amdgcn_readfirstlane(offA[r]);
        int end = __builtin_amdgcn_readfirstlane(offA[r + 1]);
        float4v acc = (float4v){0.f, 0.f, 0.f, 0.f};
        int j = off;
        // align j to 8-pixel boundary with scalar singles
        while (j < end && (j & 7)) {
            unsigned up = __builtin_amdgcn_readfirstlane(plw[j >> 1]);
            unsigned p = (j & 1) ? (up >> 16) : (up & 0xffffu);
            acc += cvt4(*(const uint2*)(xT + ((size_t)p << 8) + lo4));
            ++j;
        }
        if (j + 16 <= end) {
            uint4 q0 = plq[j >> 3];
            uint4 q1 = plq[(j >> 3) + 1];
            for (; j + 16 <= end; ) {
                int jn = j + 16;
                uint4 n0, n1;
                bool more = (jn + 16 <= end);
                if (more) {                        // prefetch next group's indices
                    n0 = plq[jn >> 3];
                    n1 = plq[(jn >> 3) + 1];
                }
                unsigned w0 = __builtin_amdgcn_readfirstlane(q0.x);
                unsigned w1 = __builtin_amdgcn_readfirstlane(q0.y);
                unsigned w2 = __builtin_amdgcn_readfirstlane(q0.z);
                unsigned w3 = __builtin_amdgcn_readfirstlane(q0.w);
                unsigned w4 = __builtin_amdgcn_readfirstlane(q1.x);
                unsigned w5 = __builtin_amdgcn_readfirstlane(q1.y);
                unsigned w6 = __builtin_amdgcn_readfirstlane(q1.z);
                unsigned w7 = __builtin_amdgcn_readfirstlane(q1.w);
                uint2 u0 = *(const uint2*)(xT + ((size_t)(w0 & 0xffffu) << 8) + lo4);
                uint2 u1 = *(const uint2*)(xT + ((size_t)(w0 >> 16)     << 8) + lo4);
                uint2 u2 = *(const uint2*)(xT + ((size_t)(w1 & 0xffffu) << 8) + lo4);
                uint2 u3 = *(const uint2*)(xT + ((size_t)(w1 >> 16)     << 8) + lo4);
                uint2 u4 = *(const uint2*)(xT + ((size_t)(w2 & 0xffffu) << 8) + lo4);
                uint2 u5 = *(const uint2*)(xT + ((size_t)(w2 >> 16)     << 8) + lo4);
                uint2 u6 = *(const uint2*)(xT + ((size_t)(w3 & 0xffffu) << 8) + lo4);
                uint2 u7 = *(const uint2*)(xT + ((size_t)(w3 >> 16)     << 8) + lo4);
                uint2 u8 = *(const uint2*)(xT + ((size_t)(w4 & 0xffffu) << 8) + lo4);
                uint2 u9 = *(const uint2*)(xT + ((size_t)(w4 >> 16)     << 8) + lo4);
                uint2 ua = *(const uint2*)(xT + ((size_t)(w5 & 0xffffu) << 8) + lo4);
                uint2 ub = *(const uint2*)(xT + ((size_t)(w5 >> 16)     << 8) + lo4);
                uint2 uc = *(const uint2*)(xT + ((size_t)(w6 & 0xffffu) << 8) + lo4);
                uint2 ud = *(const uint2*)(xT + ((size_t)(w6 >> 16)     << 8) + lo4);
                uint2 ue = *(const uint2*)(xT + ((size_t)(w7 & 0xffffu) << 8) + lo4);
                uint2 uf = *(const uint2*)(xT + ((size_t)(w7 >> 16)     << 8) + lo4);
                acc += cvt4(u0); acc += cvt4(u1); acc += cvt4(u2); acc += cvt4(u3);
                acc += cvt4(u4); acc += cvt4(u5); acc += cvt4(u6); acc += cvt4(u7);
                acc += cvt4(u8); acc += cvt4(u9); acc += cvt4(ua); acc += cvt4(ub);
                acc += cvt4(uc); acc += cvt4(ud); acc += cvt4(ue); acc += cvt4(uf);
                q0 = n0; q1 = n1; j = jn;
            }
        }
        for (; j + 8 <= end; j += 8) {
            uint4 q0 = plq[j >> 3];
            unsigned w0 = __builtin_amdgcn_readfirstlane(q0.x);
            unsigned w1 = __builtin_amdgcn_readfirstlane(q0.y);
            unsigned w2 = __builtin_amdgcn_readfirstlane(q0.z);
            unsigned w3 = __builtin_amdgcn_readfirstlane(q0.w);
            uint2 u0 = *(const uint2*)(xT + ((size_t)(w0 & 0xffffu) << 8) + lo4);
            uint2 u1 = *(const uint2*)(xT + ((size_t)(w0 >> 16)     << 8) + lo4);
            uint2 u2 = *(const uint2*)(xT + ((size_t)(w1 & 0xffffu) << 8) + lo4);
            uint2 u3 = *(const uint2*)(xT + ((size_t)(w1 >> 16)     << 8) + lo4);
            uint2 u4 = *(const uint2*)(xT + ((size_t)(w2 & 0xffffu) << 8) + lo4);
            uint2 u5 = *(const uint2*)(xT + ((size_t)(w2 >> 16)     << 8) + lo4);
            uint2 u6 = *(const uint2*)(xT + ((size_t)(w3 & 0xffffu) << 8) + lo4);
            uint2 u7 = *(const uint2*)(xT + ((size_t)(w3 >> 16)     << 8) + lo4);
            acc += cvt4(u0); acc += cvt4(u1); acc += cvt4(u2); acc += cvt4(u3);
            acc += cvt4(u4); acc += cvt4(u5); acc += cvt4(u6); acc += cvt4(u7);
        }
        while (j < end) {
            unsigned up = __builtin_amdgcn_readfirstlane(plw[j >> 1]);
            unsigned p = (j & 1) ? (up >> 16) : (up & 0xffffu);
            acc += cvt4(*(const uint2*)(xT + ((size_t)p << 8) + lo4));
            ++j;
        }
        unsigned lo = (unsigned)f2b(acc.x) | ((unsigned)f2b(acc.y) << 16);
        unsigned hi = (unsigned)f2b(acc.z) | ((unsigned)f2b(acc.w) << 16);
        *(uint2*)(ht0 + obase + (size_t)r * NC + lo4) = (uint2){lo, hi};
    }
}

// ---- depthwise (9,1) conv + bias + relu: register sliding window along a ----
__global__ __launch_bounds__(256) void k_conv1(const ushort_t* __restrict__ ht0,
                                               const float* __restrict__ w1,
                                               const float* __restrict__ b1,
                                               ushort_t* __restrict__ bufA) {
    int t = threadIdx.x, c = t & 63;
    int r = blockIdx.x;              // 0..181
    int a0 = blockIdx.y * 30;        // output angle base (real coords)
    float wr[9];
#pragma unroll
    for (int k = 0; k < 9; ++k) wr[k] = w1[c * 9 + k];
    float bb = b1[c];
    const ushort_t* ip = ht0 + ((size_t)a0 * R_BINS + r) * NC + t;
    float v[38];
#pragma unroll
    for (int j = 0; j < 38; ++j) v[j] = b2f(ip[(size_t)j * (R_BINS * NC)]);
    ushort_t* op = bufA + ((size_t)(a0 + 4) * R_BINS + r) * NC + t;
#pragma unroll
    for (int i = 0; i < 30; ++i) {
        float s = bb;
#pragma unroll
        for (int k = 0; k < 9; ++k) s = fmaf(v[i + k], wr[k], s);
        op[(size_t)i * (R_BINS * NC)] = f2b(fmaxf(s, 0.f));
    }
}

// ---- dense (9,1) conv as MFMA GEMM: B staged in LDS, 64 rows/wave ----
__global__ __launch_bounds__(256) void k_gemm(const ushort_t* __restrict__ in,
                                              const ushort_t* __restrict__ wb,
                                              const float* __restrict__ bias,
                                              ushort_t* __restrict__ out,
                                              int outRowOff) {
    __shared__ ushort_t Bs[36864];   // 73.7 KB -> 2 blocks/CU
    int t = threadIdx.x, lane = t & 63, wv = t >> 6;
    {
        const uint4* src = (const uint4*)wb;
        uint4* dst = (uint4*)Bs;
        for (int i = t; i < 36864 / 8; i += 256) dst[i] = src[i];
    }
    __syncthreads();
    int m = lane & 15, q = lane >> 4;
    int n = blockIdx.y;
    int rowBase = blockIdx.x * 256 + wv * 64;
    const ushort_t* inN = in + n * 64;
    size_t rof[4];
#pragma unroll
    for (int tl = 0; tl < 4; ++tl) {
        int row = rowBase + tl * 16 + m;
        int rowc = row < MROWS ? row : (MROWS - 1);
        rof[tl] = (size_t)rowc * NC;
    }
    float4v acc[4][4];
#pragma unroll
    for (int tl = 0; tl < 4; ++tl)
#pragma unroll
        for (int i = 0; i < 4; ++i) acc[tl][i] = (float4v){0.f, 0.f, 0.f, 0.f};

#pragma unroll
    for (int k = 0; k < 9; ++k) {
#pragma unroll
        for (int h = 0; h < 2; ++h) {
            const ushort_t* base = inN + (size_t)k * (R_BINS * NC) + h * 32 + q * 8;
            short8 af0 = *(const short8*)(base + rof[0]);
            short8 af1 = *(const short8*)(base + rof[1]);
            short8 af2 = *(const short8*)(base + rof[2]);
            short8 af3 = *(const short8*)(base + rof[3]);
            const ushort_t* bl = Bs + (size_t)((k * 2 + h) * 4) * 512 + lane * 8;
            short8 b0 = *(const short8*)(bl);
            short8 b1v = *(const short8*)(bl + 512);
            short8 b2v = *(const short8*)(bl + 1024);
            short8 b3v = *(const short8*)(bl + 1536);
            acc[0][0] = __builtin_amdgcn_mfma_f32_16x16x32_bf16(af0, b0, acc[0][0], 0, 0, 0);
            acc[0][1] = __builtin_amdgcn_mfma_f32_16x16x32_bf16(af0, b1v, acc[0][1], 0, 0, 0);
            acc[0][2] = __builtin_amdgcn_mfma_f32_16x16x32_bf16(af0, b2v, acc[0][2], 0, 0, 0);
            acc[0][3] = __builtin_amdgcn_mfma_f32_16x16x32_bf16(af0, b3v, acc[0][3], 0, 0, 0);
            acc[1][0] = __builtin_amdgcn_mfma_f32_16x16x32_bf16(af1, b0, acc[1][0], 0, 0, 0);
            acc[1][1] = __builtin_amdgcn_mfma_f32_16x16x32_bf16(af1, b1v, acc[1][1], 0, 0, 0);
            acc[1][2] = __builtin_amdgcn_mfma_f32_16x16x32_bf16(af1, b2v, acc[1][2], 0, 0, 0);
            acc[1][3] = __builtin_amdgcn_mfma_f32_16x16x32_bf16(af1, b3v, acc[1][3], 0, 0, 0);
            acc[2][0] = __builtin_amdgcn_mfma_f32_16x16x32_bf16(af2, b0, acc[2][0], 0, 0, 0);
            acc[2][1] = __builtin_amdgcn_mfma_f32_16x16x32_bf16(af2, b1v, acc[2][1], 0, 0, 0);
            acc[2][2] = __builtin_amdgcn_mfma_f32_16x16x32_bf16(af2, b2v, acc[2][2], 0, 0, 0);
            acc[2][3] = __builtin_amdgcn_mfma_f32_16x16x32_bf16(af2, b3v, acc[2][3], 0, 0, 0);
            acc[3][0] = __builtin_amdgcn_mfma_f32_16x16x32_bf16(af3, b0, acc[3][0], 0, 0, 0);
            acc[3][1] = __builtin_amdgcn_mfma_f32_16x16x32_bf16(af3, b1v, acc[3][1], 0, 0, 0);
            acc[3][2] = __builtin_amdgcn_mfma_f32_16x16x32_bf16(af3, b2v, acc[3][2], 0, 0, 0);
            acc[3][3] = __builtin_amdgcn_mfma_f32_16x16x32_bf16(af3, b3v, acc[3][3], 0, 0, 0);
        }
    }

    ushort_t* outN = out + n * 64;
#pragma unroll
    for (int tl = 0; tl < 4; ++tl) {
#pragma unroll
        for (int cot = 0; cot < 4; ++cot) {
            int co = cot * 16 + m;
            float bv = bias[co];
#pragma unroll
            for (int i = 0; i < 4; ++i) {
                int rowD = rowBase + tl * 16 + q * 4 + i;
                float v = fmaxf(acc[tl][cot][i] + bv, 0.f);
                if (rowD < MROWS) outN[(size_t)(rowD + outRowOff) * NC + co] = f2b(v);
            }
        }
    }
}

// ---- inverse DHT v4: depth-3 modulo-scheduled register pipeline, branch-free ----
// rho staged in LDS (unioned with output tile); per angle slot: consume gathers
// issued 3 slots ago while 16 newer gathers stay in flight. No barriers in loop.
union SharedIdht {
    int rhoL[A_BINS * 32];          // 23040 B, [a][px]
    float tile[2 * 256 * 33];       // 67584 B, [grp][nc][px] (used after loop)
};

#define IDHT_LOAD(S, ang) do { \
    int4 rv0_ = *(const int4*)&u.rhoL[(ang) * 32 + wq * 8]; \
    int4 rv1_ = *(const int4*)&u.rhoL[(ang) * 32 + wq * 8 + 4]; \
    int rrs_[8] = {rv0_.x, rv0_.y, rv0_.z, rv0_.w, rv1_.x, rv1_.y, rv1_.z, rv1_.w}; \
    const ushort_t* bA_ = buf3 + (size_t)(ang) * (R_BINS * NC); \
    _Pragma("unroll") \
    for (int i_ = 0; i_ < 8; ++i_) { \
        int r_ = __builtin_amdgcn_readfirstlane(rrs_[i_]); \
        S[i_] = *(const uint2*)(bA_ + (size_t)r_ * NC + lo4); \
    } } while (0)

#define IDHT_CONSUME(S) do { \
    _Pragma("unroll") \
    for (int i_ = 0; i_ < 8; ++i_) accv[i_] += cvt4(S[i_]); \
    } while (0)

__global__ __launch_bounds__(512, 2) void k_idht(const ushort_t* __restrict__ buf3,
                                                 const int* __restrict__ rho,
                                                 float* __restrict__ outp) {
    __shared__ SharedIdht u;
    int t = threadIdx.x, lane = t & 63, wv = t >> 6;   // wv 0..7
    int grp = wv >> 2;       // angle half: 0 -> 0..89, 1 -> 90..179
    int wq = wv & 3;         // pixel quad: pixels wq*8 .. wq*8+7
    int P0 = blockIdx.x * 32;
    int lo4 = lane << 2;
    // stage rho[180][32] for this block's pixels
    for (int i = t; i < A_BINS * 32; i += 512) {
        int a = i >> 5, px = i & 31;
        u.rhoL[a * 32 + px] = rho[(size_t)a * HW + P0 + px];
    }
    __syncthreads();
    float4v accv[8];
#pragma unroll
    for (int i = 0; i < 8; ++i) accv[i] = (float4v){0.f, 0.f, 0.f, 0.f};
    int a0 = grp * 90;

    uint2 S0[8], S1[8], S2[8];
    IDHT_LOAD(S0, a0);
    IDHT_LOAD(S1, a0 + 1);
    IDHT_LOAD(S2, a0 + 2);
    // steady: k = 0,3,...,84 -> consumes a0..a0+86, loads a0+3..a0+89
    for (int k = 0; k <= 84; k += 3) {
        IDHT_CONSUME(S0); IDHT_LOAD(S0, a0 + k + 3);
        IDHT_CONSUME(S1); IDHT_LOAD(S1, a0 + k + 4);
        IDHT_CONSUME(S2); IDHT_LOAD(S2, a0 + k + 5);
    }
    IDHT_CONSUME(S0);   // a0+87
    IDHT_CONSUME(S1);   // a0+88
    IDHT_CONSUME(S2);   // a0+89

    __syncthreads();    // all waves done reading rhoL; tile aliases it
#pragma unroll
    for (int i = 0; i < 8; ++i) {
        int px = wq * 8 + i;
#pragma unroll
        for (int c = 0; c < 4; ++c)
            u.tile[(size_t)grp * 8448 + (lane * 4 + c) * 33 + px] = accv[i][c];
    }
    __syncthreads();
    int px = t & 31, nc0 = t >> 5;    // nc0 0..15
    float* on = outp + P0 + px;
#pragma unroll
    for (int k = 0; k < 16; ++k) {
        int nc = nc0 + k * 16;
        on[(size_t)nc * HW] = u.tile[nc * 33 + px] + u.tile[8448 + nc * 33 + px];
    }
}

extern "C" void kernel_launch(void* const* d_in, const int* in_sizes, int n_in,
                              void* d_out, int out_size, void* d_ws, size_t ws_size,
                              hipStream_t stream) {
    const float* x   = (const float*)d_in[0];
    const int*   rho = (const int*)d_in[1];
    const float* w1  = (const float*)d_in[2];
    const float* b1  = (const float*)d_in[3];
    const float* w2  = (const float*)d_in[4];
    const float* b2  = (const float*)d_in[5];
    const float* w3  = (const float*)d_in[6];
    const float* b3  = (const float*)d_in[7];
    float* outp = (float*)d_out;

    char* ws = (char*)d_ws;
    size_t off = 0;
    auto alloc = [&](size_t bytes) -> void* {
        void* p = ws + off;
        off = (off + bytes + 255) & ~(size_t)255;
        return p;
    };
    ushort_t* xT    = (ushort_t*)alloc((size_t)HW * NC * 2);             // 8 MB
    ushort_t* ht0   = (ushort_t*)alloc((size_t)AP * R_BINS * NC * 2);    // 17.5 MB
    ushort_t* bufA  = (ushort_t*)alloc((size_t)AP * R_BINS * NC * 2);    // 17.5 MB
    ushort_t* bufB  = (ushort_t*)alloc((size_t)AP * R_BINS * NC * 2);    // 17.5 MB
    ushort_t* buf3  = (ushort_t*)alloc((size_t)A_BINS * R_BINS * NC * 2);// 16.8 MB
    ushort_t* w2b   = (ushort_t*)alloc(36864 * 2);
    ushort_t* w3b   = (ushort_t*)alloc(36864 * 2);
    int*      offs  = (int*)alloc((size_t)A_BINS * (R_BINS + 1) * 4);    // 132 KB
    ushort_t* plist = (ushort_t*)alloc((size_t)A_BINS * HW * 2);         // 5.9 MB

    k_transpose<<<dim3(256, 4), 256, 0, stream>>>(x, xT);
    k_setup<<<312, 256, 0, stream>>>(ht0, bufA, bufB, w2, w3, w2b, w3b);
    k_csr<<<A_BINS, 256, 0, stream>>>(rho, offs, plist);
    k_dht_g4<<<dim3(A_BINS, 16), 256, 0, stream>>>(xT, offs, plist, ht0);
    k_conv1<<<dim3(R_BINS, 6), 256, 0, stream>>>(ht0, w1, b1, bufA);
    k_gemm<<<dim3(128, NB), 256, 0, stream>>>(bufA, w2b, b2, bufB, 728);
    k_gemm<<<dim3(128, NB), 256, 0, stream>>>(bufB, w3b, b3, buf3, 0);
    k_idht<<<dim3(512), 512, 0, stream>>>(buf3, rho, outp);
}

// Round 12
// 373.918 us; speedup vs baseline: 1.1595x; 1.0296x over previous
//
#include <hip/hip_runtime.h>

typedef unsigned short ushort_t;
typedef __attribute__((ext_vector_type(8))) short short8;
typedef __attribute__((ext_vector_type(4))) float float4v;

#define HW 16384
#define A_BINS 180
#define R_BINS 182
#define AP 188              // A padded by 4 each side
#define CCH 64
#define NB 4
#define NC 256              // NB*CCH, nc-major inner dim of hough buffers
#define MROWS (A_BINS * R_BINS)      // 32760
#define MPROWS (AP * R_BINS)         // 34216

static __device__ __forceinline__ float b2f(ushort_t u) {
    union { unsigned u32; float f; } c; c.u32 = ((unsigned)u) << 16; return c.f;
}
static __device__ __forceinline__ float u2f(unsigned u) {
    union { unsigned u32; float f; } c; c.u32 = u; return c.f;
}
static __device__ __forceinline__ ushort_t f2b(float f) {
    union { float f; unsigned u; } c; c.f = f;
    unsigned r = c.u + 0x7fffu + ((c.u >> 16) & 1u);   // RNE
    return (ushort_t)(r >> 16);
}
static __device__ __forceinline__ float4v cvt4(uint2 u) {
    return (float4v){u2f(u.x << 16), u2f(u.x & 0xffff0000u),
                     u2f(u.y << 16), u2f(u.y & 0xffff0000u)};
}

// ---------------- transpose x [256][16384] f32 -> xT [16384][256] bf16 ----------------
__global__ __launch_bounds__(256) void k_transpose(const float* __restrict__ x,
                                                   ushort_t* __restrict__ xT) {
    __shared__ float tile[64][65];
    int t = threadIdx.x, lane = t & 63, g = t >> 6;
    int pBase = blockIdx.x * 64;     // pixel tile
    int ncBase = blockIdx.y * 64;    // channel tile
#pragma unroll
    for (int i = 0; i < 16; ++i) {
        int ncl = g + i * 4;
        tile[ncl][lane] = x[(size_t)(ncBase + ncl) * HW + pBase + lane];
    }
    __syncthreads();
#pragma unroll
    for (int i = 0; i < 16; ++i) {
        int pl = g + i * 4;
        xT[(size_t)(pBase + pl) * 256 + ncBase + lane] = f2b(tile[lane][pl]);
    }
}

// ---- setup: zero A-pad rows (blocks 0..23) + repack weights (blocks 24..311) ----
__global__ __launch_bounds__(256) void k_setup(ushort_t* __restrict__ ht0,
                                               ushort_t* __restrict__ bufA,
                                               ushort_t* __restrict__ bufB,
                                               const float* __restrict__ w2,
                                               const float* __restrict__ w3,
                                               ushort_t* __restrict__ w2b,
                                               ushort_t* __restrict__ w3b) {
    int blk = blockIdx.x, t = threadIdx.x;
    if (blk < 24) {
        int b = blk >> 3, j = blk & 7;
        int ap = (j < 4) ? j : (184 + (j - 4));
        ushort_t* base = (b == 0 ? ht0 : (b == 1 ? bufA : bufB));
        uint4* p = (uint4*)(base + (size_t)ap * (R_BINS * NC));
        int n16 = R_BINS * NC / 8;
        for (int i = t; i < n16; i += 256) p[i] = (uint4){0, 0, 0, 0};
        return;
    }
    int rep = blk - 24;                  // 0..287
    const float* w = (rep >= 144) ? w3 : w2;
    ushort_t* wb = (rep >= 144) ? w3b : w2b;
    int idx = (rep % 144) * 256 + t;     // 0..36863
    int j = idx & 7;
    int lane = (idx >> 3) & 63;
    int cot = (idx >> 9) & 3;
    int h = (idx >> 11) & 1;
    int k = idx >> 12;
    int co = cot * 16 + (lane & 15);
    int ci = h * 32 + (lane >> 4) * 8 + j;
    wb[idx] = f2b(w[(co * 64 + ci) * 9 + k]);
}

// ---- build per-angle CSR: bin -> pixel list; LDS-staged, coalesced output ----
__global__ __launch_bounds__(256) void k_csr(const int* __restrict__ rho,
                                             int* __restrict__ offs,
                                             ushort_t* __restrict__ plist) {
    __shared__ int hist[4][R_BINS];    // per-wave sub-histograms
    __shared__ int tot[R_BINS];
    __shared__ int offl[R_BINS + 1];
    __shared__ int cur[4][R_BINS];
    __shared__ ushort_t sp[HW];        // 32 KB staging, bin-sorted pixel ids
    int a = blockIdx.x, t = threadIdx.x, lane = t & 63, wv = t >> 6;
    for (int i = t; i < 4 * R_BINS; i += 256) ((int*)hist)[i] = 0;
    __syncthreads();
    const int* rA = rho + (size_t)a * HW;
#pragma unroll 4
    for (int i = 0; i < 64; ++i) {
        int r = rA[t + i * 256];
        atomicAdd(&hist[wv][r], 1);
    }
    __syncthreads();
    if (t < R_BINS) tot[t] = hist[0][t] + hist[1][t] + hist[2][t] + hist[3][t];
    __syncthreads();
    if (wv == 0) {                       // wave-parallel exclusive scan, 3 bins/lane
        int b0 = lane * 3;
        int c0 = (b0     < R_BINS) ? tot[b0]     : 0;
        int c1 = (b0 + 1 < R_BINS) ? tot[b0 + 1] : 0;
        int c2 = (b0 + 2 < R_BINS) ? tot[b0 + 2] : 0;
        int sum = c0 + c1 + c2, inc = sum;
#pragma unroll
        for (int d = 1; d < 64; d <<= 1) {
            int vv = __shfl_up(inc, d);
            if (lane >= d) inc += vv;
        }
        int excl = inc - sum;
        if (b0     < R_BINS) offl[b0]     = excl;
        if (b0 + 1 < R_BINS) offl[b0 + 1] = excl + c0;
        if (b0 + 2 < R_BINS) offl[b0 + 2] = excl + c0 + c1;
        if (lane == 63) offl[R_BINS] = inc;
    }
    __syncthreads();
    if (t < R_BINS) {
        int b = offl[t];
        cur[0][t] = b; b += hist[0][t];
        cur[1][t] = b; b += hist[1][t];
        cur[2][t] = b; b += hist[2][t];
        cur[3][t] = b;
    }
    if (t <= R_BINS) offs[a * (R_BINS + 1) + t] = offl[t];
    __syncthreads();
#pragma unroll 4
    for (int i = 0; i < 64; ++i) {
        int p = t + i * 256;
        int r = rA[p];
        int pos = atomicAdd(&cur[wv][r], 1);
        sp[pos] = (ushort_t)p;
    }
    __syncthreads();
    const uint4* spv = (const uint4*)sp;
    uint4* plv = (uint4*)(plist + (size_t)a * HW);
    for (int i = t; i < HW / 8; i += 256) plv[i] = spv[i];
}

// ---- DHT gather v5: half-channel blocks (XCD-L2 residency) + scalarized
// 2-pixel wave-gathers. Lanes 0-31 gather pixel-even's 128-nc slice, lanes
// 32-63 pixel-odd's; per-bin combine = 4x shfl(lane^32). Pixel indices and
// select operands are SGPRs (readfirstlane); ~3 VALU addr per pair.
__global__ __launch_bounds__(256, 4) void k_dht_g4(const ushort_t* __restrict__ xT,
                                                   const int* __restrict__ offs,
                                                   const ushort_t* __restrict__ plist,
                                                   ushort_t* __restrict__ ht0) {
    int ax = blockIdx.x;               // 0..359
    int a = ax >> 1, half = ax & 1;
    int part = blockIdx.y;             // 0..15
    int t = threadIdx.x, lane = t & 63, wv = t >> 6;
    int wslot = part * 4 + wv;         // 0..63
    int lh = lane & 31;
    bool lowhalf = (lane < 32);
    int lh4 = lh * 4;                  // my 4 nc within the 128-nc half
    const ushort_t* xh = xT + half * 128;
    const uint*  plw = (const uint*)(plist + (size_t)a * HW);
    const uint4* plq = (const uint4*)plw;
    const int* offA = offs + a * (R_BINS + 1);
    size_t obase = (size_t)(a + 4) * (R_BINS * NC) + half * 128;
    for (int r = wslot; r < R_BINS; r += 64) {
        int off = __builtin_amdgcn_readfirstlane(offA[r]);
        int end = __builtin_amdgcn_readfirstlane(offA[r + 1]);
        float4v acc = (float4v){0.f, 0.f, 0.f, 0.f};
        int j = off;
        if (j < end && (j & 1)) {      // odd leading single (aligns to pairs)
            unsigned up = __builtin_amdgcn_readfirstlane(plw[j >> 1]);
            unsigned p = up >> 16;
            uint2 u = *(const uint2*)(xh + (size_t)p * 256 + lh4);
            if (lowhalf) acc += cvt4(u);
            ++j;
        }
        while (j + 2 <= end && (j & 7)) {   // pairs until 8-aligned
            unsigned w = __builtin_amdgcn_readfirstlane(plw[j >> 1]);
            unsigned pe = w & 0xffffu, po = w >> 16;
            unsigned ps = lowhalf ? pe : po;
            uint2 u = *(const uint2*)(xh + (size_t)ps * 256 + lh4);
            acc += cvt4(u);
            j += 2;
        }
        if (j + 16 <= end) {           // main: 16 pixels = 8 pairs, idx prefetch
            uint4 q0 = plq[j >> 3];
            uint4 q1 = plq[(j >> 3) + 1];
            for (; j + 16 <= end; ) {
                int jn = j + 16;
                uint4 n0, n1;
                bool more = (jn + 16 <= end);
                if (more) {
                    n0 = plq[jn >> 3];
                    n1 = plq[(jn >> 3) + 1];
                }
                unsigned w0 = __builtin_amdgcn_readfirstlane(q0.x);
                unsigned w1 = __builtin_amdgcn_readfirstlane(q0.y);
                unsigned w2 = __builtin_amdgcn_readfirstlane(q0.z);
                unsigned w3 = __builtin_amdgcn_readfirstlane(q0.w);
                unsigned w4 = __builtin_amdgcn_readfirstlane(q1.x);
                unsigned w5 = __builtin_amdgcn_readfirstlane(q1.y);
                unsigned w6 = __builtin_amdgcn_readfirstlane(q1.z);
                unsigned w7 = __builtin_amdgcn_readfirstlane(q1.w);
                unsigned s0 = lowhalf ? (w0 & 0xffffu) : (w0 >> 16);
                unsigned s1 = lowhalf ? (w1 & 0xffffu) : (w1 >> 16);
                unsigned s2 = lowhalf ? (w2 & 0xffffu) : (w2 >> 16);
                unsigned s3 = lowhalf ? (w3 & 0xffffu) : (w3 >> 16);
                unsigned s4 = lowhalf ? (w4 & 0xffffu) : (w4 >> 16);
                unsigned s5 = lowhalf ? (w5 & 0xffffu) : (w5 >> 16);
                unsigned s6 = lowhalf ? (w6 & 0xffffu) : (w6 >> 16);
                unsigned s7 = lowhalf ? (w7 & 0xffffu) : (w7 >> 16);
                uint2 u0 = *(const uint2*)(xh + (size_t)s0 * 256 + lh4);
                uint2 u1 = *(const uint2*)(xh + (size_t)s1 * 256 + lh4);
                uint2 u2 = *(const uint2*)(xh + (size_t)s2 * 256 + lh4);
                uint2 u3 = *(const uint2*)(xh + (size_t)s3 * 256 + lh4);
                uint2 u4 = *(const uint2*)(xh + (size_t)s4 * 256 + lh4);
                uint2 u5 = *(const uint2*)(xh + (size_t)s5 * 256 + lh4);
                uint2 u6 = *(const uint2*)(xh + (size_t)s6 * 256 + lh4);
                uint2 u7 = *(const uint2*)(xh + (size_t)s7 * 256 + lh4);
                acc += cvt4(u0); acc += cvt4(u1); acc += cvt4(u2); acc += cvt4(u3);
                acc += cvt4(u4); acc += cvt4(u5); acc += cvt4(u6); acc += cvt4(u7);
                q0 = n0; q1 = n1; j = jn;
            }
        }
        for (; j + 8 <= end; j += 8) { // 8-pixel group = 4 pairs
            uint4 q = plq[j >> 3];
            unsigned w0 = __builtin_amdgcn_readfirstlane(q.x);
            unsigned w1 = __builtin_amdgcn_readfirstlane(q.y);
            unsigned w2 = __builtin_amdgcn_readfirstlane(q.z);
            unsigned w3 = __builtin_amdgcn_readfirstlane(q.w);
            unsigned s0 = lowhalf ? (w0 & 0xffffu) : (w0 >> 16);
            unsigned s1 = lowhalf ? (w1 & 0xffffu) : (w1 >> 16);
            unsigned s2 = lowhalf ? (w2 & 0xffffu) : (w2 >> 16);
            unsigned s3 = lowhalf ? (w3 & 0xffffu) : (w3 >> 16);
            uint2 u0 = *(const uint2*)(xh + (size_t)s0 * 256 + lh4);
            uint2 u1 = *(const uint2*)(xh + (size_t)s1 * 256 + lh4);
            uint2 u2 = *(const uint2*)(xh + (size_t)s2 * 256 + lh4);
            uint2 u3 = *(const uint2*)(xh + (size_t)s3 * 256 + lh4);
            acc += cvt4(u0); acc += cvt4(u1); acc += cvt4(u2); acc += cvt4(u3);
        }
        while (j + 2 <= end) {         // tail pairs
            unsigned w = __builtin_amdgcn_readfirstlane(plw[j >> 1]);
            unsigned pe = w & 0xffffu, po = w >> 16;
            unsigned ps = lowhalf ? pe : po;
            uint2 u = *(const uint2*)(xh + (size_t)ps * 256 + lh4);
            acc += cvt4(u);
            j += 2;
        }
        if (j < end) {                 // tail single (even j -> low 16 bits)
            unsigned up = __builtin_amdgcn_readfirstlane(plw[j >> 1]);
            unsigned p = up & 0xffffu;
            uint2 u = *(const uint2*)(xh + (size_t)p * 256 + lh4);
            if (lowhalf) acc += cvt4(u);
        }
        // combine even/odd pixel partials across half-waves
        float4v oth;
        oth.x = __shfl(acc.x, lane ^ 32);
        oth.y = __shfl(acc.y, lane ^ 32);
        oth.z = __shfl(acc.z, lane ^ 32);
        oth.w = __shfl(acc.w, lane ^ 32);
        acc += oth;
        if (lowhalf) {
            unsigned lo = (unsigned)f2b(acc.x) | ((unsigned)f2b(acc.y) << 16);
            unsigned hi = (unsigned)f2b(acc.z) | ((unsigned)f2b(acc.w) << 16);
            *(uint2*)(ht0 + obase + (size_t)r * NC + lh4) = (uint2){lo, hi};
        }
    }
}

// ---- depthwise (9,1) conv + bias + relu: register sliding window along a ----
__global__ __launch_bounds__(256) void k_conv1(const ushort_t* __restrict__ ht0,
                                               const float* __restrict__ w1,
                                               const float* __restrict__ b1,
                                               ushort_t* __restrict__ bufA) {
    int t = threadIdx.x, c = t & 63;
    int r = blockIdx.x;              // 0..181
    int a0 = blockIdx.y * 30;        // output angle base (real coords)
    float wr[9];
#pragma unroll
    for (int k = 0; k < 9; ++k) wr[k] = w1[c * 9 + k];
    float bb = b1[c];
    const ushort_t* ip = ht0 + ((size_t)a0 * R_BINS + r) * NC + t;
    float v[38];
#pragma unroll
    for (int j = 0; j < 38; ++j) v[j] = b2f(ip[(size_t)j * (R_BINS * NC)]);
    ushort_t* op = bufA + ((size_t)(a0 + 4) * R_BINS + r) * NC + t;
#pragma unroll
    for (int i = 0; i < 30; ++i) {
        float s = bb;
#pragma unroll
        for (int k = 0; k < 9; ++k) s = fmaf(v[i + k], wr[k], s);
        op[(size_t)i * (R_BINS * NC)] = f2b(fmaxf(s, 0.f));
    }
}

// ---- dense (9,1) conv as MFMA GEMM: B staged in LDS, 64 rows/wave ----
__global__ __launch_bounds__(256) void k_gemm(const ushort_t* __restrict__ in,
                                              const ushort_t* __restrict__ wb,
                                              const float* __restrict__ bias,
                                              ushort_t* __restrict__ out,
                                              int outRowOff) {
    __shared__ ushort_t Bs[36864];   // 73.7 KB -> 2 blocks/CU
    int t = threadIdx.x, lane = t & 63, wv = t >> 6;
    {
        const uint4* src = (const uint4*)wb;
        uint4* dst = (uint4*)Bs;
        for (int i = t; i < 36864 / 8; i += 256) dst[i] = src[i];
    }
    __syncthreads();
    int m = lane & 15, q = lane >> 4;
    int n = blockIdx.y;
    int rowBase = blockIdx.x * 256 + wv * 64;
    const ushort_t* inN = in + n * 64;
    size_t rof[4];
#pragma unroll
    for (int tl = 0; tl < 4; ++tl) {
        int row = rowBase + tl * 16 + m;
        int rowc = row < MROWS ? row : (MROWS - 1);
        rof[tl] = (size_t)rowc * NC;
    }
    float4v acc[4][4];
#pragma unroll
    for (int tl = 0; tl < 4; ++tl)
#pragma unroll
        for (int i = 0; i < 4; ++i) acc[tl][i] = (float4v){0.f, 0.f, 0.f, 0.f};

#pragma unroll
    for (int k = 0; k < 9; ++k) {
#pragma unroll
        for (int h = 0; h < 2; ++h) {
            const ushort_t* base = inN + (size_t)k * (R_BINS * NC) + h * 32 + q * 8;
            short8 af0 = *(const short8*)(base + rof[0]);
            short8 af1 = *(const short8*)(base + rof[1]);
            short8 af2 = *(const short8*)(base + rof[2]);
            short8 af3 = *(const short8*)(base + rof[3]);
            const ushort_t* bl = Bs + (size_t)((k * 2 + h) * 4) * 512 + lane * 8;
            short8 b0 = *(const short8*)(bl);
            short8 b1v = *(const short8*)(bl + 512);
            short8 b2v = *(const short8*)(bl + 1024);
            short8 b3v = *(const short8*)(bl + 1536);
            acc[0][0] = __builtin_amdgcn_mfma_f32_16x16x32_bf16(af0, b0, acc[0][0], 0, 0, 0);
            acc[0][1] = __builtin_amdgcn_mfma_f32_16x16x32_bf16(af0, b1v, acc[0][1], 0, 0, 0);
            acc[0][2] = __builtin_amdgcn_mfma_f32_16x16x32_bf16(af0, b2v, acc[0][2], 0, 0, 0);
            acc[0][3] = __builtin_amdgcn_mfma_f32_16x16x32_bf16(af0, b3v, acc[0][3], 0, 0, 0);
            acc[1][0] = __builtin_amdgcn_mfma_f32_16x16x32_bf16(af1, b0, acc[1][0], 0, 0, 0);
            acc[1][1] = __builtin_amdgcn_mfma_f32_16x16x32_bf16(af1, b1v, acc[1][1], 0, 0, 0);
            acc[1][2] = __builtin_amdgcn_mfma_f32_16x16x32_bf16(af1, b2v, acc[1][2], 0, 0, 0);
            acc[1][3] = __builtin_amdgcn_mfma_f32_16x16x32_bf16(af1, b3v, acc[1][3], 0, 0, 0);
            acc[2][0] = __builtin_amdgcn_mfma_f32_16x16x32_bf16(af2, b0, acc[2][0], 0, 0, 0);
            acc[2][1] = __builtin_amdgcn_mfma_f32_16x16x32_bf16(af2, b1v, acc[2][1], 0, 0, 0);
            acc[2][2] = __builtin_amdgcn_mfma_f32_16x16x32_bf16(af2, b2v, acc[2][2], 0, 0, 0);
            acc[2][3] = __builtin_amdgcn_mfma_f32_16x16x32_bf16(af2, b3v, acc[2][3], 0, 0, 0);
            acc[3][0] = __builtin_amdgcn_mfma_f32_16x16x32_bf16(af3, b0, acc[3][0], 0, 0, 0);
            acc[3][1] = __builtin_amdgcn_mfma_f32_16x16x32_bf16(af3, b1v, acc[3][1], 0, 0, 0);
            acc[3][2] = __builtin_amdgcn_mfma_f32_16x16x32_bf16(af3, b2v, acc[3][2], 0, 0, 0);
            acc[3][3] = __builtin_amdgcn_mfma_f32_16x16x32_bf16(af3, b3v, acc[3][3], 0, 0, 0);
        }
    }

    ushort_t* outN = out + n * 64;
#pragma unroll
    for (int tl = 0; tl < 4; ++tl) {
#pragma unroll
        for (int cot = 0; cot < 4; ++cot) {
            int co = cot * 16 + m;
            float bv = bias[co];
#pragma unroll
            for (int i = 0; i < 4; ++i) {
                int rowD = rowBase + tl * 16 + q * 4 + i;
                float v = fmaxf(acc[tl][cot][i] + bv, 0.f);
                if (rowD < MROWS) outN[(size_t)(rowD + outRowOff) * NC + co] = f2b(v);
            }
        }
    }
}

// ---- inverse DHT v4: depth-3 modulo-scheduled register pipeline, branch-free ----
union SharedIdht {
    int rhoL[A_BINS * 32];          // 23040 B, [a][px]
    float tile[2 * 256 * 33];       // 67584 B, [grp][nc][px] (used after loop)
};

#define IDHT_LOAD(S, ang) do { \
    int4 rv0_ = *(const int4*)&u.rhoL[(ang) * 32 + wq * 8]; \
    int4 rv1_ = *(const int4*)&u.rhoL[(ang) * 32 + wq * 8 + 4]; \
    int rrs_[8] = {rv0_.x, rv0_.y, rv0_.z, rv0_.w, rv1_.x, rv1_.y, rv1_.z, rv1_.w}; \
    const ushort_t* bA_ = buf3 + (size_t)(ang) * (R_BINS * NC); \
    _Pragma("unroll") \
    for (int i_ = 0; i_ < 8; ++i_) { \
        int r_ = __builtin_amdgcn_readfirstlane(rrs_[i_]); \
        S[i_] = *(const uint2*)(bA_ + (size_t)r_ * NC + lo4); \
    } } while (0)

#define IDHT_CONSUME(S) do { \
    _Pragma("unroll") \
    for (int i_ = 0; i_ < 8; ++i_) accv[i_] += cvt4(S[i_]); \
    } while (0)

__global__ __launch_bounds__(512, 2) void k_idht(const ushort_t* __restrict__ buf3,
                                                 const int* __restrict__ rho,
                                                 float* __restrict__ outp) {
    __shared__ SharedIdht u;
    int t = threadIdx.x, lane = t & 63, wv = t >> 6;   // wv 0..7
    int grp = wv >> 2;       // angle half: 0 -> 0..89, 1 -> 90..179
    int wq = wv & 3;         // pixel quad: pixels wq*8 .. wq*8+7
    int P0 = blockIdx.x * 32;
    int lo4 = lane << 2;
    for (int i = t; i < A_BINS * 32; i += 512) {
        int a = i >> 5, px = i & 31;
        u.rhoL[a * 32 + px] = rho[(size_t)a * HW + P0 + px];
    }
    __syncthreads();
    float4v accv[8];
#pragma unroll
    for (int i = 0; i < 8; ++i) accv[i] = (float4v){0.f, 0.f, 0.f, 0.f};
    int a0 = grp * 90;

    uint2 S0[8], S1[8], S2[8];
    IDHT_LOAD(S0, a0);
    IDHT_LOAD(S1, a0 + 1);
    IDHT_LOAD(S2, a0 + 2);
    for (int k = 0; k <= 84; k += 3) {
        IDHT_CONSUME(S0); IDHT_LOAD(S0, a0 + k + 3);
        IDHT_CONSUME(S1); IDHT_LOAD(S1, a0 + k + 4);
        IDHT_CONSUME(S2); IDHT_LOAD(S2, a0 + k + 5);
    }
    IDHT_CONSUME(S0);   // a0+87
    IDHT_CONSUME(S1);   // a0+88
    IDHT_CONSUME(S2);   // a0+89

    __syncthreads();    // all waves done reading rhoL; tile aliases it
#pragma unroll
    for (int i = 0; i < 8; ++i) {
        int px = wq * 8 + i;
#pragma unroll
        for (int c = 0; c < 4; ++c)
            u.tile[(size_t)grp * 8448 + (lane * 4 + c) * 33 + px] = accv[i][c];
    }
    __syncthreads();
    int px = t & 31, nc0 = t >> 5;    // nc0 0..15
    float* on = outp + P0 + px;
#pragma unroll
    for (int k = 0; k < 16; ++k) {
        int nc = nc0 + k * 16;
        on[(size_t)nc * HW] = u.tile[nc * 33 + px] + u.tile[8448 + nc * 33 + px];
    }
}

extern "C" void kernel_launch(void* const* d_in, const int* in_sizes, int n_in,
                              void* d_out, int out_size, void* d_ws, size_t ws_size,
                              hipStream_t stream) {
    const float* x   = (const float*)d_in[0];
    const int*   rho = (const int*)d_in[1];
    const float* w1  = (const float*)d_in[2];
    const float* b1  = (const float*)d_in[3];
    const float* w2  = (const float*)d_in[4];
    const float* b2  = (const float*)d_in[5];
    const float* w3  = (const float*)d_in[6];
    const float* b3  = (const float*)d_in[7];
    float* outp = (float*)d_out;

    char* ws = (char*)d_ws;
    size_t off = 0;
    auto alloc = [&](size_t bytes) -> void* {
        void* p = ws + off;
        off = (off + bytes + 255) & ~(size_t)255;
        return p;
    };
    ushort_t* xT    = (ushort_t*)alloc((size_t)HW * NC * 2);             // 8 MB
    ushort_t* ht0   = (ushort_t*)alloc((size_t)AP * R_BINS * NC * 2);    // 17.5 MB
    ushort_t* bufA  = (ushort_t*)alloc((size_t)AP * R_BINS * NC * 2);    // 17.5 MB
    ushort_t* bufB  = (ushort_t*)alloc((size_t)AP * R_BINS * NC * 2);    // 17.5 MB
    ushort_t* buf3  = (ushort_t*)alloc((size_t)A_BINS * R_BINS * NC * 2);// 16.8 MB
    ushort_t* w2b   = (ushort_t*)alloc(36864 * 2);
    ushort_t* w3b   = (ushort_t*)alloc(36864 * 2);
    int*      offs  = (int*)alloc((size_t)A_BINS * (R_BINS + 1) * 4);    // 132 KB
    ushort_t* plist = (ushort_t*)alloc((size_t)A_BINS * HW * 2);         // 5.9 MB

    k_transpose<<<dim3(256, 4), 256, 0, stream>>>(x, xT);
    k_setup<<<312, 256, 0, stream>>>(ht0, bufA, bufB, w2, w3, w2b, w3b);
    k_csr<<<A_BINS, 256, 0, stream>>>(rho, offs, plist);
    k_dht_g4<<<dim3(360, 16), 256, 0, stream>>>(xT, offs, plist, ht0);
    k_conv1<<<dim3(R_BINS, 6), 256, 0, stream>>>(ht0, w1, b1, bufA);
    k_gemm<<<dim3(128, NB), 256, 0, stream>>>(bufA, w2b, b2, bufB, 728);
    k_gemm<<<dim3(128, NB), 256, 0, stream>>>(bufB, w3b, b3, buf3, 0);
    k_idht<<<dim3(512), 512, 0, stream>>>(buf3, rho, outp);
}